// Round 2
// baseline (248.659 us; speedup 1.0000x reference)
//
#include <hip/hip_runtime.h>
#include <hip/hip_bf16.h>
#include <stdint.h>

// AnchorAttention on MI355X. Inputs/outputs fp32; internal compute bf16 MFMA + fp32 accum.
// Pipeline: ln_stats -> ln_apply(+transpose, ->bf16) -> cvt weights -> gemm<0> QKVA
//           -> flash x2 -> gemm<1> proj+bias+residual (fp32 out).

using bf16 = __bf16;
typedef __bf16 bf16x4 __attribute__((ext_vector_type(4)));
typedef __bf16 bf16x8 __attribute__((ext_vector_type(8)));
typedef float f32x4 __attribute__((ext_vector_type(4)));

#define DIMC 512
#define NTOK 1024
#define NB 8
#define NH 8
#define HD 64

__device__ __forceinline__ void gload_lds16(const bf16* g, bf16* l) {
  __builtin_amdgcn_global_load_lds((__attribute__((address_space(1))) void*)g,
                                   (__attribute__((address_space(3))) void*)l,
                                   16, 0, 0);
}

// ---------------- LN stats: mu/rstd per token, fp32 inputs ----------------
__global__ __launch_bounds__(256) void k_ln_stats(
    const float* __restrict__ r, const float* __restrict__ z,
    float* __restrict__ mu, float* __restrict__ rs) {
  int t = blockIdx.x * 256 + threadIdx.x;  // [tensor][b][n]
  int tensor = t >> 13;
  int b = (t >> 10) & 7;
  int n = t & 1023;
  const float* x = (tensor ? z : r) + (size_t)b * DIMC * NTOK + n;
  float s = 0.f, ss = 0.f;
#pragma unroll 8
  for (int c = 0; c < DIMC; ++c) {
    float v = x[(size_t)c * NTOK];
    s += v; ss += v * v;
  }
  float m = s * (1.0f / DIMC);
  float var = ss * (1.0f / DIMC) - m * m;
  mu[t] = m;
  rs[t] = rsqrtf(var + 1e-5f);
}

// ---------------- LN apply + transpose [B,C,N]f32 -> [B,N,C]bf16 ----------------
__global__ __launch_bounds__(256) void k_ln_apply(
    const float* __restrict__ r, const float* __restrict__ z,
    const float* __restrict__ wr, const float* __restrict__ br,
    const float* __restrict__ wz, const float* __restrict__ bz,
    const float* __restrict__ mu, const float* __restrict__ rs,
    bf16* __restrict__ rf, bf16* __restrict__ zf) {
  __shared__ __align__(16) bf16 T[64 * 72];  // [n][c] tile, padded stride 72
  int bt = blockIdx.z;
  int tensor = bt & 1, b = bt >> 1;
  const float* x   = tensor ? z  : r;
  const float* w   = tensor ? wz : wr;
  const float* bia = tensor ? bz : br;
  bf16* out = tensor ? zf : rf;
  int n0 = blockIdx.x * 64, c0 = blockIdx.y * 64;
  const float* muP = mu + (tensor << 13) + (b << 10) + n0;
  const float* rsP = rs + (tensor << 13) + (b << 10) + n0;
  int tid = threadIdx.x;
  int cl = tid >> 3;          // 0..31
  int nl = (tid & 7) * 8;     // 0..56
#pragma unroll
  for (int pass = 0; pass < 2; ++pass) {
    int c = c0 + pass * 32 + cl;
    float wc = w[c], bc = bia[c];
    const float* src = x + ((size_t)(b * DIMC + c)) * NTOK + n0 + nl;
    float4 v0 = *reinterpret_cast<const float4*>(src);
    float4 v1 = *reinterpret_cast<const float4*>(src + 4);
    float vv[8] = {v0.x, v0.y, v0.z, v0.w, v1.x, v1.y, v1.z, v1.w};
#pragma unroll
    for (int j = 0; j < 8; ++j) {
      int n = nl + j;
      float val = (vv[j] - muP[n]) * rsP[n] * wc + bc;
      T[n * 72 + pass * 32 + cl] = (bf16)val;
    }
  }
  __syncthreads();
  int nr = tid >> 3;
  int cc = (tid & 7) * 8;
#pragma unroll
  for (int pass = 0; pass < 2; ++pass) {
    int n = pass * 32 + nr;
    bf16x8 o;
#pragma unroll
    for (int j = 0; j < 8; ++j) o[j] = T[n * 72 + cc + j];
    *reinterpret_cast<bf16x8*>(out + ((size_t)(b * NTOK + n0 + n)) * DIMC + c0 + cc) = o;
  }
}

// ---------------- weight convert fp32 -> bf16, 5 matrices of 512x512 ----------------
__global__ __launch_bounds__(256) void k_cvt5(
    const float* __restrict__ W0, const float* __restrict__ W1,
    const float* __restrict__ W2, const float* __restrict__ W3,
    const float* __restrict__ W4, bf16* __restrict__ out) {
  int m = blockIdx.y;
  const float* W = (m == 0) ? W0 : (m == 1) ? W1 : (m == 2) ? W2 : (m == 3) ? W3 : W4;
  bf16* o = out + (size_t)m * DIMC * DIMC;
  int i = blockIdx.x * 256 + threadIdx.x;  // quad index, 65536 total
  float4 v = reinterpret_cast<const float4*>(W)[i];
  bf16x4 b;
  b[0] = (bf16)v.x; b[1] = (bf16)v.y; b[2] = (bf16)v.z; b[3] = (bf16)v.w;
  *reinterpret_cast<bf16x4*>(o + (size_t)i * 4) = b;
}

// ---------------- GEMM (bt): out[m,n] = sum_k A[m,k]*B[n,k], 128x128 tile, BK=32 ----------------
// MODE 0: A = ln tensor [1024,512], B = Wbf[mat]; store bf16 -> qkva [mat][b][h][n][d]
// MODE 1: A = Wproj bf16, B = attn2[b] [1024,512]; store fp32 -> d_out[b][o][n] + bias + residual z
template <int MODE>
__global__ __launch_bounds__(256) void k_gemm(
    const bf16* __restrict__ rf, const bf16* __restrict__ zf,
    const bf16* __restrict__ Wbf,
    void* __restrict__ outbase,
    const float* __restrict__ zres, const float* __restrict__ bproj) {
  __shared__ __align__(16) bf16 As[128 * 32];
  __shared__ __align__(16) bf16 Bs[128 * 32];
  int b = blockIdx.z;
  const bf16 *Ap, *Bp;
  int m0, n0;
  if (MODE == 0) {
    int mat = blockIdx.y;
    Ap = (mat < 2 ? rf : zf) + (size_t)b * NTOK * DIMC;
    Bp = Wbf + (size_t)mat * DIMC * DIMC;
    m0 = (blockIdx.x >> 2) * 128;  // token tile (M=1024)
    n0 = (blockIdx.x & 3) * 128;   // out-chan tile (N=512)
  } else {
    Ap = Wbf + (size_t)4 * DIMC * DIMC;        // Wproj
    Bp = rf + (size_t)b * NTOK * DIMC;         // attn2 for this b
    m0 = (blockIdx.x >> 3) * 128;  // o tile (M=512)
    n0 = (blockIdx.x & 7) * 128;   // token tile (N=1024)
  }
  int tid = threadIdx.x;
  int w = tid >> 6, l = tid & 63;
  int wm = (w >> 1) * 64, wn = (w & 1) * 64;
  int lr = l & 15, lg = l >> 4;
  int srow = l >> 2;          // staging row within 16-row group
  int scol = (l & 3) * 8;     // staging k element offset
  f32x4 acc[4][4] = {};

  for (int kt = 0; kt < 16; ++kt) {
    int k0 = kt * 32;
#pragma unroll
    for (int q = 0; q < 2; ++q) {
      int rowA = w * 32 + q * 16 + srow;
      gload_lds16(Ap + (size_t)(m0 + rowA) * DIMC + k0 + scol, &As[(w * 32 + q * 16) * 32]);
      gload_lds16(Bp + (size_t)(n0 + rowA) * DIMC + k0 + scol, &Bs[(w * 32 + q * 16) * 32]);
    }
    __syncthreads();
    bf16x8 af[4], bfr[4];
#pragma unroll
    for (int i = 0; i < 4; ++i)
      af[i] = *reinterpret_cast<const bf16x8*>(&As[(wm + 16 * i + lr) * 32 + lg * 8]);
#pragma unroll
    for (int j = 0; j < 4; ++j)
      bfr[j] = *reinterpret_cast<const bf16x8*>(&Bs[(wn + 16 * j + lr) * 32 + lg * 8]);
#pragma unroll
    for (int i = 0; i < 4; ++i)
#pragma unroll
      for (int j = 0; j < 4; ++j)
        acc[i][j] = __builtin_amdgcn_mfma_f32_16x16x32_bf16(af[i], bfr[j], acc[i][j], 0, 0, 0);
    __syncthreads();
  }

#pragma unroll
  for (int i = 0; i < 4; ++i) {
#pragma unroll
    for (int j = 0; j < 4; ++j) {
#pragma unroll
      for (int rr = 0; rr < 4; ++rr) {
        int mm = m0 + wm + 16 * i + lg * 4 + rr;
        int nn = n0 + wn + 16 * j + lr;
        if (MODE == 0) {
          // mm = token, nn = out channel -> qkva[mat][b][h][n][d], bf16
          bf16* outp = (bf16*)outbase + (size_t)blockIdx.y * ((size_t)NB * NH * NTOK * HD)
                       + (size_t)b * (NH * NTOK * HD);
          outp[((size_t)((nn >> 6) * NTOK + mm)) * HD + (nn & 63)] = (bf16)acc[i][j][rr];
        } else {
          // mm = o, nn = token -> d_out[b][o][n] = acc + bproj[o] + z[b][o][n], fp32
          float* outp = (float*)outbase + (size_t)b * DIMC * NTOK;
          const float* zp = zres + (size_t)b * DIMC * NTOK;
          size_t idx = (size_t)mm * NTOK + nn;
          outp[idx] = acc[i][j][rr] + bproj[mm] + zp[idx];
        }
      }
    }
  }
}

// ---------------- Flash attention: softmax(Q K^T * 0.125) V, N=1024, D=64 ----------------
// grid (16 q-tiles, 64 bh). out_mode 0: [bh][n][d]; out_mode 1: [b][n][h*64+d]
__global__ __launch_bounds__(256) void k_flash(
    const bf16* __restrict__ Qp, const bf16* __restrict__ Kp,
    const bf16* __restrict__ Vp, bf16* __restrict__ Op, int out_mode) {
  __shared__ __align__(16) bf16 Qs[64 * 64];
  __shared__ __align__(16) bf16 Ks[64 * 64];
  __shared__ __align__(16) bf16 Vts[64 * 64];   // transposed: [d][key]
  __shared__ __align__(16) bf16 Ps[4 * 16 * 64];
  int q0 = blockIdx.x * 64;
  int bh = blockIdx.y;
  const bf16* Qb = Qp + (size_t)bh * NTOK * HD;
  const bf16* Kb = Kp + (size_t)bh * NTOK * HD;
  const bf16* Vb = Vp + (size_t)bh * NTOK * HD;
  int tid = threadIdx.x;
  int w = tid >> 6, l = tid & 63;
  int lr = l & 15, lg = l >> 4;
  int sr = tid >> 3;            // 0..31 staging row
  int sc = (tid & 7) * 8;       // 0..56 staging col

  // stage Q tile once (XOR-swizzled rows: elem col ^= (row&7)*8)
#pragma unroll
  for (int pass = 0; pass < 2; ++pass) {
    int row = pass * 32 + sr;
    bf16x8 v = *reinterpret_cast<const bf16x8*>(Qb + (size_t)(q0 + row) * HD + sc);
    *reinterpret_cast<bf16x8*>(&Qs[row * 64 + (sc ^ ((row & 7) * 8))]) = v;
  }

  float mrow[4], lrow[4];
  f32x4 of[4] = {};
#pragma unroll
  for (int rr = 0; rr < 4; ++rr) { mrow[rr] = -1e30f; lrow[rr] = 0.f; }

  for (int kt = 0; kt < 16; ++kt) {
    int k0 = kt * 64;
#pragma unroll
    for (int pass = 0; pass < 2; ++pass) {
      int row = pass * 32 + sr;
      bf16x8 kv = *reinterpret_cast<const bf16x8*>(Kb + (size_t)(k0 + row) * HD + sc);
      *reinterpret_cast<bf16x8*>(&Ks[row * 64 + (sc ^ ((row & 7) * 8))]) = kv;
      bf16x8 vv = *reinterpret_cast<const bf16x8*>(Vb + (size_t)(k0 + row) * HD + sc);
#pragma unroll
      for (int j = 0; j < 8; ++j) {
        int d = sc + j;
        Vts[d * 64 + (row ^ ((d & 7) * 8))] = vv[j];
      }
    }
    __syncthreads();

    // S tile: this wave's 16 q-rows x 64 keys
    f32x4 sf[4] = {};
    int qrow = w * 16 + lr;
#pragma unroll
    for (int s = 0; s < 2; ++s) {
      bf16x8 aq = *reinterpret_cast<const bf16x8*>(
          &Qs[qrow * 64 + ((s * 32 + lg * 8) ^ ((qrow & 7) * 8))]);
#pragma unroll
      for (int f = 0; f < 4; ++f) {
        int krow = 16 * f + lr;
        bf16x8 bk = *reinterpret_cast<const bf16x8*>(
            &Ks[krow * 64 + ((s * 32 + lg * 8) ^ ((krow & 7) * 8))]);
        sf[f] = __builtin_amdgcn_mfma_f32_16x16x32_bf16(aq, bk, sf[f], 0, 0, 0);
      }
    }

    // online softmax: rows = w*16 + lg*4 + rr, cols = 16f + lr
#pragma unroll
    for (int rr = 0; rr < 4; ++rr) {
      float mx = -1e30f;
#pragma unroll
      for (int f = 0; f < 4; ++f) {
        sf[f][rr] *= 0.125f;
        mx = fmaxf(mx, sf[f][rr]);
      }
#pragma unroll
      for (int off = 1; off < 16; off <<= 1) mx = fmaxf(mx, __shfl_xor(mx, off));
      float mnew = fmaxf(mrow[rr], mx);
      float alpha = __expf(mrow[rr] - mnew);
      mrow[rr] = mnew;
      float psum = 0.f;
#pragma unroll
      for (int f = 0; f < 4; ++f) {
        float p = __expf(sf[f][rr] - mnew);
        sf[f][rr] = p;
        psum += p;
      }
#pragma unroll
      for (int off = 1; off < 16; off <<= 1) psum += __shfl_xor(psum, off);
      lrow[rr] = lrow[rr] * alpha + psum;
#pragma unroll
      for (int g = 0; g < 4; ++g) of[g][rr] *= alpha;
    }

    // P -> LDS (bf16), per-wave region
#pragma unroll
    for (int rr = 0; rr < 4; ++rr) {
      int prow = lg * 4 + rr;
#pragma unroll
      for (int f = 0; f < 4; ++f) {
        int pcol = 16 * f + lr;
        Ps[w * 1024 + prow * 64 + (pcol ^ ((prow & 7) * 8))] = (bf16)sf[f][rr];
      }
    }

    // PV: O += P[16q x 64k] @ V[64k x 64d]
#pragma unroll
    for (int s = 0; s < 2; ++s) {
      bf16x8 ap = *reinterpret_cast<const bf16x8*>(
          &Ps[w * 1024 + lr * 64 + ((s * 32 + lg * 8) ^ ((lr & 7) * 8))]);
#pragma unroll
      for (int g = 0; g < 4; ++g) {
        int vrow = 16 * g + lr;
        bf16x8 bv = *reinterpret_cast<const bf16x8*>(
            &Vts[vrow * 64 + ((s * 32 + lg * 8) ^ ((vrow & 7) * 8))]);
        of[g] = __builtin_amdgcn_mfma_f32_16x16x32_bf16(ap, bv, of[g], 0, 0, 0);
      }
    }
    __syncthreads();
  }

  // epilogue
#pragma unroll
  for (int rr = 0; rr < 4; ++rr) {
    float inv = 1.0f / lrow[rr];
    int q = q0 + w * 16 + lg * 4 + rr;
#pragma unroll
    for (int g = 0; g < 4; ++g) {
      int d = 16 * g + lr;
      float val = of[g][rr] * inv;
      if (out_mode == 0) {
        Op[(size_t)bh * NTOK * HD + (size_t)q * HD + d] = (bf16)val;
      } else {
        int b = bh >> 3, h = bh & 7;
        Op[((size_t)(b * NTOK + q)) * DIMC + h * HD + d] = (bf16)val;
      }
    }
  }
}

extern "C" void kernel_launch(void* const* d_in, const int* in_sizes, int n_in,
                              void* d_out, int out_size, void* d_ws, size_t ws_size,
                              hipStream_t stream) {
  const float* r  = (const float*)d_in[0];
  const float* z  = (const float*)d_in[1];
  const float* wr = (const float*)d_in[2];
  const float* br = (const float*)d_in[3];
  const float* wz = (const float*)d_in[4];
  const float* bz = (const float*)d_in[5];
  const float* Wq = (const float*)d_in[6];
  const float* Wk = (const float*)d_in[7];
  const float* Wv = (const float*)d_in[8];
  const float* Wa = (const float*)d_in[9];
  const float* Wp = (const float*)d_in[10];
  const float* bp = (const float*)d_in[11];

  // workspace layout (bytes):
  // mu 64K | rs 64K | rf 8M | zf 8M | qkva 32M | v1 8M | at2 8M | Wbf 2.625M   (~67 MB)
  char* ws = (char*)d_ws;
  float* mu = (float*)ws;
  float* rs = (float*)(ws + 65536);
  bf16* rf   = (bf16*)(ws + 131072);
  bf16* zf   = rf + (size_t)NB * NTOK * DIMC;
  bf16* qkva = zf + (size_t)NB * NTOK * DIMC;
  const size_t SLOT = (size_t)NB * NH * NTOK * HD;
  bf16* v1  = qkva + 4 * SLOT;
  bf16* at2 = v1 + SLOT;
  bf16* Wbf = at2 + SLOT;  // 5 x 512 x 512 bf16

  bf16* Qt = qkva;
  bf16* Kt = qkva + 1 * SLOT;
  bf16* Vt = qkva + 2 * SLOT;
  bf16* At = qkva + 3 * SLOT;

  k_ln_stats<<<64, 256, 0, stream>>>(r, z, mu, rs);
  k_ln_apply<<<dim3(16, 8, 16), 256, 0, stream>>>(r, z, wr, br, wz, bz, mu, rs, rf, zf);
  k_cvt5<<<dim3(256, 5), 256, 0, stream>>>(Wq, Wk, Wv, Wa, Wp, Wbf);
  k_gemm<0><<<dim3(32, 4, NB), 256, 0, stream>>>(rf, zf, Wbf, qkva, nullptr, nullptr);
  // stage 1: attn1 = softmax(K A^T) V  -> v1  (flash with Q:=K, K:=A, V:=V)
  k_flash<<<dim3(16, 64), 256, 0, stream>>>(Kt, At, Vt, v1, 0);
  // stage 2: attn2 = softmax(A Q^T) v1 -> at2 [b][n][c]
  k_flash<<<dim3(16, 64), 256, 0, stream>>>(At, Qt, v1, at2, 1);
  // projection + bias + residual, fp32 store direct to d_out [b][c][n]
  k_gemm<1><<<dim3(32, 1, NB), 256, 0, stream>>>(at2, nullptr, Wbf, d_out, z, bp);
}

// Round 3
// 177.189 us; speedup vs baseline: 1.4034x; 1.4034x over previous
//
#include <hip/hip_runtime.h>
#include <hip/hip_bf16.h>
#include <stdint.h>

// AnchorAttention on MI355X. Inputs/outputs fp32; internal compute bf16 MFMA + fp32 accum.
// Pipeline: ln_stats -> ln_apply(+transpose, ->bf16) -> cvt weights -> gemm<0> QKVA
//           -> flash2 x2 (8-warp 32x32 swapped-QK^T in-register softmax) -> gemm<1>.

using bf16 = __bf16;
typedef __bf16 bf16x4 __attribute__((ext_vector_type(4)));
typedef __bf16 bf16x8 __attribute__((ext_vector_type(8)));
typedef float f32x4 __attribute__((ext_vector_type(4)));
typedef float f32x16 __attribute__((ext_vector_type(16)));

#define DIMC 512
#define NTOK 1024
#define NB 8
#define NH 8
#define HD 64

__device__ __forceinline__ void gload_lds16(const bf16* g, bf16* l) {
  __builtin_amdgcn_global_load_lds((__attribute__((address_space(1))) void*)g,
                                   (__attribute__((address_space(3))) void*)l,
                                   16, 0, 0);
}

__device__ __forceinline__ float bpermf(int srclane, float v) {
  int i = __builtin_amdgcn_ds_bpermute(srclane << 2, __builtin_bit_cast(int, v));
  return __builtin_bit_cast(float, i);
}

__device__ __forceinline__ int pkbf(float lo, float hi) {
  unsigned short a = __builtin_bit_cast(unsigned short, (bf16)lo);
  unsigned short b = __builtin_bit_cast(unsigned short, (bf16)hi);
  return (int)((unsigned)a | ((unsigned)b << 16));
}

// ---------------- LN stats ----------------
__global__ __launch_bounds__(256) void k_ln_stats(
    const float* __restrict__ r, const float* __restrict__ z,
    float* __restrict__ mu, float* __restrict__ rs) {
  int t = blockIdx.x * 256 + threadIdx.x;
  int tensor = t >> 13;
  int b = (t >> 10) & 7;
  int n = t & 1023;
  const float* x = (tensor ? z : r) + (size_t)b * DIMC * NTOK + n;
  float s = 0.f, ss = 0.f;
#pragma unroll 8
  for (int c = 0; c < DIMC; ++c) {
    float v = x[(size_t)c * NTOK];
    s += v; ss += v * v;
  }
  float m = s * (1.0f / DIMC);
  float var = ss * (1.0f / DIMC) - m * m;
  mu[t] = m;
  rs[t] = rsqrtf(var + 1e-5f);
}

// ---------------- LN apply + transpose [B,C,N]f32 -> [B,N,C]bf16 ----------------
__global__ __launch_bounds__(256) void k_ln_apply(
    const float* __restrict__ r, const float* __restrict__ z,
    const float* __restrict__ wr, const float* __restrict__ br,
    const float* __restrict__ wz, const float* __restrict__ bz,
    const float* __restrict__ mu, const float* __restrict__ rs,
    bf16* __restrict__ rf, bf16* __restrict__ zf) {
  __shared__ __align__(16) bf16 T[64 * 72];
  int bt = blockIdx.z;
  int tensor = bt & 1, b = bt >> 1;
  const float* x   = tensor ? z  : r;
  const float* w   = tensor ? wz : wr;
  const float* bia = tensor ? bz : br;
  bf16* out = tensor ? zf : rf;
  int n0 = blockIdx.x * 64, c0 = blockIdx.y * 64;
  const float* muP = mu + (tensor << 13) + (b << 10) + n0;
  const float* rsP = rs + (tensor << 13) + (b << 10) + n0;
  int tid = threadIdx.x;
  int cl = tid >> 3;
  int nl = (tid & 7) * 8;
#pragma unroll
  for (int pass = 0; pass < 2; ++pass) {
    int c = c0 + pass * 32 + cl;
    float wc = w[c], bc = bia[c];
    const float* src = x + ((size_t)(b * DIMC + c)) * NTOK + n0 + nl;
    float4 v0 = *reinterpret_cast<const float4*>(src);
    float4 v1 = *reinterpret_cast<const float4*>(src + 4);
    float vv[8] = {v0.x, v0.y, v0.z, v0.w, v1.x, v1.y, v1.z, v1.w};
#pragma unroll
    for (int j = 0; j < 8; ++j) {
      int n = nl + j;
      float val = (vv[j] - muP[n]) * rsP[n] * wc + bc;
      T[n * 72 + pass * 32 + cl] = (bf16)val;
    }
  }
  __syncthreads();
  int nr = tid >> 3;
  int cc = (tid & 7) * 8;
#pragma unroll
  for (int pass = 0; pass < 2; ++pass) {
    int n = pass * 32 + nr;
    bf16x8 o;
#pragma unroll
    for (int j = 0; j < 8; ++j) o[j] = T[n * 72 + cc + j];
    *reinterpret_cast<bf16x8*>(out + ((size_t)(b * NTOK + n0 + n)) * DIMC + c0 + cc) = o;
  }
}

// ---------------- weight convert fp32 -> bf16, 5 matrices ----------------
__global__ __launch_bounds__(256) void k_cvt5(
    const float* __restrict__ W0, const float* __restrict__ W1,
    const float* __restrict__ W2, const float* __restrict__ W3,
    const float* __restrict__ W4, bf16* __restrict__ out) {
  int m = blockIdx.y;
  const float* W = (m == 0) ? W0 : (m == 1) ? W1 : (m == 2) ? W2 : (m == 3) ? W3 : W4;
  bf16* o = out + (size_t)m * DIMC * DIMC;
  int i = blockIdx.x * 256 + threadIdx.x;
  float4 v = reinterpret_cast<const float4*>(W)[i];
  bf16x4 b;
  b[0] = (bf16)v.x; b[1] = (bf16)v.y; b[2] = (bf16)v.z; b[3] = (bf16)v.w;
  *reinterpret_cast<bf16x4*>(o + (size_t)i * 4) = b;
}

// ---------------- GEMM (bt), 128x128 tile, BK=32 ----------------
template <int MODE>
__global__ __launch_bounds__(256) void k_gemm(
    const bf16* __restrict__ rf, const bf16* __restrict__ zf,
    const bf16* __restrict__ Wbf,
    void* __restrict__ outbase,
    const float* __restrict__ zres, const float* __restrict__ bproj) {
  __shared__ __align__(16) bf16 As[128 * 32];
  __shared__ __align__(16) bf16 Bs[128 * 32];
  int b = blockIdx.z;
  const bf16 *Ap, *Bp;
  int m0, n0;
  if (MODE == 0) {
    int mat = blockIdx.y;
    Ap = (mat < 2 ? rf : zf) + (size_t)b * NTOK * DIMC;
    Bp = Wbf + (size_t)mat * DIMC * DIMC;
    m0 = (blockIdx.x >> 2) * 128;
    n0 = (blockIdx.x & 3) * 128;
  } else {
    Ap = Wbf + (size_t)4 * DIMC * DIMC;
    Bp = rf + (size_t)b * NTOK * DIMC;
    m0 = (blockIdx.x >> 3) * 128;
    n0 = (blockIdx.x & 7) * 128;
  }
  int tid = threadIdx.x;
  int w = tid >> 6, l = tid & 63;
  int wm = (w >> 1) * 64, wn = (w & 1) * 64;
  int lr = l & 15, lg = l >> 4;
  int srow = l >> 2;
  int scol = (l & 3) * 8;
  f32x4 acc[4][4] = {};

  for (int kt = 0; kt < 16; ++kt) {
    int k0 = kt * 32;
#pragma unroll
    for (int q = 0; q < 2; ++q) {
      int rowA = w * 32 + q * 16 + srow;
      gload_lds16(Ap + (size_t)(m0 + rowA) * DIMC + k0 + scol, &As[(w * 32 + q * 16) * 32]);
      gload_lds16(Bp + (size_t)(n0 + rowA) * DIMC + k0 + scol, &Bs[(w * 32 + q * 16) * 32]);
    }
    __syncthreads();
    bf16x8 af[4], bfr[4];
#pragma unroll
    for (int i = 0; i < 4; ++i)
      af[i] = *reinterpret_cast<const bf16x8*>(&As[(wm + 16 * i + lr) * 32 + lg * 8]);
#pragma unroll
    for (int j = 0; j < 4; ++j)
      bfr[j] = *reinterpret_cast<const bf16x8*>(&Bs[(wn + 16 * j + lr) * 32 + lg * 8]);
#pragma unroll
    for (int i = 0; i < 4; ++i)
#pragma unroll
      for (int j = 0; j < 4; ++j)
        acc[i][j] = __builtin_amdgcn_mfma_f32_16x16x32_bf16(af[i], bfr[j], acc[i][j], 0, 0, 0);
    __syncthreads();
  }

#pragma unroll
  for (int i = 0; i < 4; ++i) {
#pragma unroll
    for (int j = 0; j < 4; ++j) {
#pragma unroll
      for (int rr = 0; rr < 4; ++rr) {
        int mm = m0 + wm + 16 * i + lg * 4 + rr;
        int nn = n0 + wn + 16 * j + lr;
        if (MODE == 0) {
          bf16* outp = (bf16*)outbase + (size_t)blockIdx.y * ((size_t)NB * NH * NTOK * HD)
                       + (size_t)b * (NH * NTOK * HD);
          outp[((size_t)((nn >> 6) * NTOK + mm)) * HD + (nn & 63)] = (bf16)acc[i][j][rr];
        } else {
          float* outp = (float*)outbase + (size_t)b * DIMC * NTOK;
          const float* zp = zres + (size_t)b * DIMC * NTOK;
          size_t idx = (size_t)mm * NTOK + nn;
          outp[idx] = acc[i][j][rr] + bproj[mm] + zp[idx];
        }
      }
    }
  }
}

// ---------------- flash2: 8 warps x QBLK=32, KVBLK=64, swapped QK^T ----------------
// S^T = mfma(K,Q): lane(q=l&31, hl=l>>5) holds P[q][k], k = kb*32 + (r&3)+8*(r>>2)+4*hl.
// Softmax in-register (defer-max, log2 domain). P packed bf16, halves exchanged via shfl_xor(32).
// PV: O[q][d] = mfma(A=Pfrag, B=V[k][d]) with V stored transposed (Vt[d][k]) in LDS.
__global__ __launch_bounds__(512) void k_flash2(
    const bf16* __restrict__ Qp, const bf16* __restrict__ Kp,
    const bf16* __restrict__ Vp, bf16* __restrict__ Op, int out_mode) {
  __shared__ __align__(16) bf16 Ks[2][64 * 64];
  __shared__ __align__(16) bf16 Vt[2][64 * 64];
  int tid = threadIdx.x;
  int w = tid >> 6, l = tid & 63;
  int hl = l >> 5, ln31 = l & 31, ln7 = l & 7;
  int bh = blockIdx.y;
  int q0 = blockIdx.x * 256;
  const bf16* Qb = Qp + (size_t)bh * NTOK * HD;
  const bf16* Kb = Kp + (size_t)bh * NTOK * HD;
  const bf16* Vb = Vp + (size_t)bh * NTOK * HD;

  // Q fragments in registers, scale folded (0.125 * log2(e)) for exp2-domain softmax
  const float QS = 0.125f * 1.44269504088896340736f;
  bf16x8 qf[4];
  int qrow = q0 + w * 32 + ln31;
#pragma unroll
  for (int s = 0; s < 4; ++s) {
    bf16x8 raw = *reinterpret_cast<const bf16x8*>(Qb + (size_t)qrow * 64 + 16 * s + 8 * hl);
#pragma unroll
    for (int j = 0; j < 8; ++j) qf[s][j] = (bf16)((float)raw[j] * QS);
  }

  // staging assignments
  int krow_st = w * 8 + (l >> 3);           // K row this lane stages
  int kcol_st = ((l & 7) ^ (l >> 3)) * 8;   // pre-swizzled source column
  int vrow_st = tid >> 3;                   // 0..63
  int vcol_st = (tid & 7) * 8;

  float m_run = -1e30f, l_run = 0.f;
  f32x16 of0{}, of1{};

  // prologue: stage tile 0
  gload_lds16(Kb + (size_t)krow_st * 64 + kcol_st, &Ks[0][w * 512]);
  {
    bf16x8 v0 = *reinterpret_cast<const bf16x8*>(Vb + (size_t)vrow_st * 64 + vcol_st);
#pragma unroll
    for (int j = 0; j < 8; ++j)
      Vt[0][(vcol_st + j) * 64 + (vrow_st ^ (j << 3))] = v0[j];
  }
  __syncthreads();

  int buf = 0;
#pragma unroll 1
  for (int kt = 0; kt < 16; ++kt) {
    bf16x8 vnext;
    if (kt + 1 < 16) {
      int k0n = (kt + 1) * 64;
      gload_lds16(Kb + (size_t)(k0n + krow_st) * 64 + kcol_st, &Ks[buf ^ 1][w * 512]);
      vnext = *reinterpret_cast<const bf16x8*>(Vb + (size_t)(k0n + vrow_st) * 64 + vcol_st);
    }

    // ---- QK^T (swapped): sT0 = k rows 0..31, sT1 = 32..63 ----
    f32x16 sT0{}, sT1{};
#pragma unroll
    for (int s = 0; s < 4; ++s) {
      int cofs = (16 * s + 8 * hl) ^ (ln7 * 8);
      bf16x8 k0f = *reinterpret_cast<const bf16x8*>(&Ks[buf][ln31 * 64 + cofs]);
      bf16x8 k1f = *reinterpret_cast<const bf16x8*>(&Ks[buf][(ln31 + 32) * 64 + cofs]);
      sT0 = __builtin_amdgcn_mfma_f32_32x32x16_bf16(k0f, qf[s], sT0, 0, 0, 0);
      sT1 = __builtin_amdgcn_mfma_f32_32x32x16_bf16(k1f, qf[s], sT1, 0, 0, 0);
    }

    // ---- softmax (log2 domain, defer-max) ----
    float a0 = -1e30f, a1 = -1e30f, a2 = -1e30f, a3 = -1e30f;
#pragma unroll
    for (int r = 0; r < 16; r += 4) {
      a0 = fmaxf(a0, sT0[r]);     a1 = fmaxf(a1, sT0[r + 1]);
      a2 = fmaxf(a2, sT0[r + 2]); a3 = fmaxf(a3, sT0[r + 3]);
      a0 = fmaxf(a0, sT1[r]);     a1 = fmaxf(a1, sT1[r + 1]);
      a2 = fmaxf(a2, sT1[r + 2]); a3 = fmaxf(a3, sT1[r + 3]);
    }
    float mx = fmaxf(fmaxf(a0, a1), fmaxf(a2, a3));
    mx = fmaxf(mx, __shfl_xor(mx, 32));
    if (!__all(mx - m_run <= 10.0f)) {
      float mnew = fmaxf(m_run, mx);
      float alpha = exp2f(m_run - mnew);
      l_run *= alpha;
      m_run = mnew;
#pragma unroll
      for (int r = 0; r < 16; ++r) {
        int qloc = (r & 3) + 8 * (r >> 2) + 4 * hl;
        float ar = bpermf(qloc + (l & 32), alpha);
        of0[r] *= ar;
        of1[r] *= ar;
      }
    }
    float s0 = 0.f, s1 = 0.f, s2 = 0.f, s3 = 0.f;
#pragma unroll
    for (int r = 0; r < 16; r += 4) {
      sT0[r]     = exp2f(sT0[r]     - m_run); s0 += sT0[r];
      sT0[r + 1] = exp2f(sT0[r + 1] - m_run); s1 += sT0[r + 1];
      sT0[r + 2] = exp2f(sT0[r + 2] - m_run); s2 += sT0[r + 2];
      sT0[r + 3] = exp2f(sT0[r + 3] - m_run); s3 += sT0[r + 3];
      sT1[r]     = exp2f(sT1[r]     - m_run); s0 += sT1[r];
      sT1[r + 1] = exp2f(sT1[r + 1] - m_run); s1 += sT1[r + 1];
      sT1[r + 2] = exp2f(sT1[r + 2] - m_run); s2 += sT1[r + 2];
      sT1[r + 3] = exp2f(sT1[r + 3] - m_run); s3 += sT1[r + 3];
    }
    float lsum = (s0 + s1) + (s2 + s3);
    lsum += __shfl_xor(lsum, 32);
    l_run += lsum;

    // ---- pack P to bf16 words: wpk[2g+i], g=0..7 (g<4 from sT0, g>=4 from sT1) ----
    int wpk[16];
#pragma unroll
    for (int g = 0; g < 4; ++g) {
      wpk[2 * g]     = pkbf(sT0[4 * g],     sT0[4 * g + 1]);
      wpk[2 * g + 1] = pkbf(sT0[4 * g + 2], sT0[4 * g + 3]);
      wpk[2 * (g + 4)]     = pkbf(sT1[4 * g],     sT1[4 * g + 1]);
      wpk[2 * (g + 4) + 1] = pkbf(sT1[4 * g + 2], sT1[4 * g + 3]);
    }
    int rw[16];
#pragma unroll
    for (int t = 0; t < 16; ++t) rw[t] = __shfl_xor(wpk[t], 32);

    // ---- assemble PV A-fragments: pf[ks] holds P[q][16ks+8hl+j], j=0..7 ----
    bf16x8 pf[4];
#pragma unroll
    for (int ks = 0; ks < 4; ++ks) {
      int gA = 2 * ks, gB = 2 * ks + 1;
      union { int i[4]; bf16x8 v; } u;
      u.i[0] = hl ? rw[2 * gB]     : wpk[2 * gA];
      u.i[1] = hl ? rw[2 * gB + 1] : wpk[2 * gA + 1];
      u.i[2] = hl ? wpk[2 * gB]     : rw[2 * gA];
      u.i[3] = hl ? wpk[2 * gB + 1] : rw[2 * gA + 1];
      pf[ks] = u.v;
    }

    // ---- write V-transpose for next tile (regs were prefetched) ----
    if (kt + 1 < 16) {
#pragma unroll
      for (int j = 0; j < 8; ++j)
        Vt[buf ^ 1][(vcol_st + j) * 64 + (vrow_st ^ (j << 3))] = vnext[j];
    }

    // ---- PV: O[q][d] accumulate ----
#pragma unroll
    for (int ks = 0; ks < 4; ++ks) {
      int cofs = (16 * ks + 8 * hl) ^ (ln7 * 8);
      bf16x8 v0f = *reinterpret_cast<const bf16x8*>(&Vt[buf][ln31 * 64 + cofs]);
      bf16x8 v1f = *reinterpret_cast<const bf16x8*>(&Vt[buf][(ln31 + 32) * 64 + cofs]);
      of0 = __builtin_amdgcn_mfma_f32_32x32x16_bf16(pf[ks], v0f, of0, 0, 0, 0);
      of1 = __builtin_amdgcn_mfma_f32_32x32x16_bf16(pf[ks], v1f, of1, 0, 0, 0);
    }

    __syncthreads();
    buf ^= 1;
  }

  // ---- epilogue: normalize and store ----
  float inv = 1.0f / l_run;
#pragma unroll
  for (int r = 0; r < 16; ++r) {
    int qloc = (r & 3) + 8 * (r >> 2) + 4 * hl;
    float invr = bpermf(qloc + (l & 32), inv);
    int q = q0 + w * 32 + qloc;
    float o0 = of0[r] * invr;
    float o1 = of1[r] * invr;
    if (out_mode == 0) {
      bf16* p = Op + (size_t)bh * NTOK * HD + (size_t)q * 64;
      p[ln31] = (bf16)o0;
      p[ln31 + 32] = (bf16)o1;
    } else {
      int b = bh >> 3, h = bh & 7;
      bf16* p = Op + ((size_t)(b * NTOK + q)) * DIMC + h * 64;
      p[ln31] = (bf16)o0;
      p[ln31 + 32] = (bf16)o1;
    }
  }
}

extern "C" void kernel_launch(void* const* d_in, const int* in_sizes, int n_in,
                              void* d_out, int out_size, void* d_ws, size_t ws_size,
                              hipStream_t stream) {
  const float* r  = (const float*)d_in[0];
  const float* z  = (const float*)d_in[1];
  const float* wr = (const float*)d_in[2];
  const float* br = (const float*)d_in[3];
  const float* wz = (const float*)d_in[4];
  const float* bz = (const float*)d_in[5];
  const float* Wq = (const float*)d_in[6];
  const float* Wk = (const float*)d_in[7];
  const float* Wv = (const float*)d_in[8];
  const float* Wa = (const float*)d_in[9];
  const float* Wp = (const float*)d_in[10];
  const float* bp = (const float*)d_in[11];

  char* ws = (char*)d_ws;
  float* mu = (float*)ws;
  float* rs = (float*)(ws + 65536);
  bf16* rf   = (bf16*)(ws + 131072);
  bf16* zf   = rf + (size_t)NB * NTOK * DIMC;
  bf16* qkva = zf + (size_t)NB * NTOK * DIMC;
  const size_t SLOT = (size_t)NB * NH * NTOK * HD;
  bf16* v1  = qkva + 4 * SLOT;
  bf16* at2 = v1 + SLOT;
  bf16* Wbf = at2 + SLOT;

  bf16* Qt = qkva;
  bf16* Kt = qkva + 1 * SLOT;
  bf16* Vv = qkva + 2 * SLOT;
  bf16* At = qkva + 3 * SLOT;

  k_ln_stats<<<64, 256, 0, stream>>>(r, z, mu, rs);
  k_ln_apply<<<dim3(16, 8, 16), 256, 0, stream>>>(r, z, wr, br, wz, bz, mu, rs, rf, zf);
  k_cvt5<<<dim3(256, 5), 256, 0, stream>>>(Wq, Wk, Wv, Wa, Wp, Wbf);
  k_gemm<0><<<dim3(32, 4, NB), 256, 0, stream>>>(rf, zf, Wbf, qkva, nullptr, nullptr);
  // stage 1: softmax(K A^T) V -> v1
  k_flash2<<<dim3(4, 64), 512, 0, stream>>>(Kt, At, Vv, v1, 0);
  // stage 2: softmax(A Q^T) v1 -> at2 [b][n][c]
  k_flash2<<<dim3(4, 64), 512, 0, stream>>>(At, Qt, v1, at2, 1);
  // projection + bias + residual
  k_gemm<1><<<dim3(32, 1, NB), 256, 0, stream>>>(at2, nullptr, Wbf, d_out, z, bp);
}